// Round 6
// baseline (16417.166 us; speedup 1.0000x reference)
//
#include <hip/hip_runtime.h>
#include <stdint.h>

#define S_LEN 8192
#define DIM   2048
#define W2    4096   // W row length = 2*DIM

typedef __attribute__((ext_vector_type(8))) __bf16 bf16x8;
typedef __attribute__((ext_vector_type(4))) float  floatx4;
typedef __attribute__((ext_vector_type(2))) float  f32x2;
typedef unsigned long long u64;
typedef unsigned int       u32;

// ---------------------------------------------------------------------------
// Init: tag buffers. buf0 = s_0 = -1.0 with tag 0; buf1 tag 0 (never matches
// its first expected tag 1, so readers spin until written).
// ---------------------------------------------------------------------------
__global__ void init_pairs(u64* __restrict__ pairs) {
  int i = blockIdx.x * 256 + threadIdx.x;
  if (i < 2 * DIM) {
    pairs[i] = ((u64)__float_as_uint(-1.0f) << 32) | 0ull;
  }
}

// ---------------------------------------------------------------------------
// GEMM: C[m][n] = sum_k A[m][k] * W[n*4096 + 2048 + k] + b[n]
// (unchanged — correct, and small vs the recurrence)
// ---------------------------------------------------------------------------
__device__ inline bf16x8 pack_bf8(float4 a, float4 b) {
  bf16x8 h;
  h[0] = (__bf16)a.x; h[1] = (__bf16)a.y; h[2] = (__bf16)a.z; h[3] = (__bf16)a.w;
  h[4] = (__bf16)b.x; h[5] = (__bf16)b.y; h[6] = (__bf16)b.z; h[7] = (__bf16)b.w;
  return h;
}

__global__ __launch_bounds__(256) void gemm_ctx(const float* __restrict__ A,
                                                const float* __restrict__ W,
                                                const float* __restrict__ bias,
                                                float* __restrict__ C) {
  __shared__ __bf16 As[64][72];
  __shared__ __bf16 Bs[64][72];
  const int tid  = threadIdx.x;
  const int m0   = blockIdx.y * 64;
  const int n0   = blockIdx.x * 64;
  const int w    = tid >> 6;
  const int lane = tid & 63;
  const int wm   = w >> 1, wn = w & 1;
  const int r    = tid >> 2;
  const int seg  = tid & 3;

  floatx4 acc[2][2] = {};

  for (int k0 = 0; k0 < DIM; k0 += 64) {
    {
      const float* pa = A + (size_t)(m0 + r) * DIM + k0 + seg * 16;
      const float* pb = W + (size_t)(n0 + r) * W2 + DIM + k0 + seg * 16;
      float4 a0 = ((const float4*)pa)[0], a1 = ((const float4*)pa)[1];
      float4 a2 = ((const float4*)pa)[2], a3 = ((const float4*)pa)[3];
      float4 b0 = ((const float4*)pb)[0], b1 = ((const float4*)pb)[1];
      float4 b2 = ((const float4*)pb)[2], b3 = ((const float4*)pb)[3];
      *(bf16x8*)&As[r][seg * 16]     = pack_bf8(a0, a1);
      *(bf16x8*)&As[r][seg * 16 + 8] = pack_bf8(a2, a3);
      *(bf16x8*)&Bs[r][seg * 16]     = pack_bf8(b0, b1);
      *(bf16x8*)&Bs[r][seg * 16 + 8] = pack_bf8(b2, b3);
    }
    __syncthreads();
    #pragma unroll
    for (int kk = 0; kk < 64; kk += 32) {
      const int ks = kk + (lane >> 4) * 8;
      bf16x8 af[2], bfr[2];
      af[0]  = *(const bf16x8*)&As[32 * wm +      (lane & 15)][ks];
      af[1]  = *(const bf16x8*)&As[32 * wm + 16 + (lane & 15)][ks];
      bfr[0] = *(const bf16x8*)&Bs[32 * wn +      (lane & 15)][ks];
      bfr[1] = *(const bf16x8*)&Bs[32 * wn + 16 + (lane & 15)][ks];
      #pragma unroll
      for (int im = 0; im < 2; ++im)
        #pragma unroll
        for (int in = 0; in < 2; ++in)
          acc[im][in] = __builtin_amdgcn_mfma_f32_16x16x32_bf16(
              af[im], bfr[in], acc[im][in], 0, 0, 0);
    }
    __syncthreads();
  }

  #pragma unroll
  for (int in = 0; in < 2; ++in) {
    const int col = n0 + 32 * wn + 16 * in + (lane & 15);
    const float bv = bias[col];
    #pragma unroll
    for (int im = 0; im < 2; ++im) {
      const int rbase = m0 + 32 * wm + 16 * im + (lane >> 4) * 4;
      #pragma unroll
      for (int q = 0; q < 4; ++q)
        C[(size_t)(rbase + q) * DIM + col] = acc[im][in][q] + bv;
    }
  }
}

// DPP butterfly add: x += x_from_lane(partner), partner an involution within
// the 16-lane row -> direction-proof (every lane ends with the row total).
// 0xB1 = quad_perm:[1,0,3,2] (xor1)   0x4E = quad_perm:[2,3,0,1] (xor2)
// 0x141 = row_half_mirror (i^7 in 8)  0x140 = row_mirror (i^15 in 16)
template <int CTRL>
__device__ __forceinline__ float dpp_add(float x) {
  int s = __builtin_amdgcn_update_dpp(0, __float_as_int(x), CTRL, 0xF, 0xF, true);
  return x + __int_as_float(s);
}

// ---------------------------------------------------------------------------
// Persistent recurrence v8: 64 WGs x 1024 threads (16 waves). WG k owns rows
// [32k, 32k+32); wave w owns 2 rows (2w, 2w+1); lane l owns cols [32l,32l+32).
// vs v7 (FAILED): reduce direction bug fixed. v7 used row_shr:N which sources
// lane i-N (AMD scan convention: total lands at lane 15), so owner lane 0
// kept only its own partial -> absmax 4.39. Now a DPP BUTTERFLY (quad_perm
// xor1/xor2, row_half_mirror, row_mirror) — each level an involution, all
// lanes get the row total, owners at lanes 0/32 correct by symmetry.
// vs v6 (15.55ms):
//   - 1024-thread WGs: per-lane W slab 128 -> 64 floats. v6's VGPR_Count=84
//     < 128-float slab => slab was NOT arch-VGPR-resident. 64 floats/lane is
//     unambiguously register-resident. Same total FLOPs, same per-SIMD
//     issue, same 64-producer ring; per-thread poll 4 -> 2 pairs.
//   - reduce: xor32 scatter (1 shfl) + xor16 butterfly (1 shfl) + 4x DPP
//     butterfly adds (VALU speed) instead of 6 LDS-path shfls.
// POLL IS v4's EXACT FORM (sacred): both attempts to change its instruction
// form regressed via FETCH_SIZE blowup (v3 +134MB, v5 +260MB).
// ---------------------------------------------------------------------------
__global__ __launch_bounds__(1024, 1) void recur(const float* __restrict__ W,
                                                 const float* __restrict__ ce,
                                                 float* __restrict__ out,
                                                 u64* __restrict__ pairs) {
  __shared__ __align__(16) float st[2][DIM];
  const int tid = threadIdx.x;
  const int w = tid >> 6, l = tid & 63;
  const int i0 = blockIdx.x * 32;

  // W_state slab into registers: 2 rows x 16 f32x2 (32 cols) per lane
  f32x2 w2[2][16];
  #pragma unroll
  for (int r2 = 0; r2 < 2; ++r2) {
    const float* wp = W + (size_t)(i0 + 2 * w + r2) * W2 + 32 * l;
    #pragma unroll
    for (int j = 0; j < 8; ++j) {
      float4 v = ((const float4*)wp)[j];
      w2[r2][2 * j + 0] = (f32x2){v.x, v.y};
      w2[r2][2 * j + 1] = (f32x2){v.z, v.w};
    }
  }

  const int myrow = i0 + 2 * w + (l >> 5);  // valid when owner
  const bool owner = ((l & 31) == 0);       // lanes 0 and 32 of each wave
  float hcm = -3.0e38f;                     // running cummax
  float s_last = 0.f;
  u64* b0 = pairs;
  u64* b1 = pairs + DIM;
  const int base = tid * 2;                 // 1024 threads x 2 pairs = 2048
  // LDS store slot (float index) — swizzle chosen so that the rotated read
  // (float4 at 32l + 4*(jj^(l&7))) retrieves CANONICAL cols 32l+4jj, keeping
  // the w2 register index compile-time. Derivation: canonical float4 block F
  // is stored at F ^ ((F>>3)&7); here F = tid>>1, half h = tid&1.
  const int Fp    = (tid >> 1) ^ ((tid >> 4) & 7);
  const int slot2 = 4 * Fp + 2 * (tid & 1);

  // step-1 operands (prefetched before the loop)
  float cev = 0.f, cxv = 0.f;
  if (owner) {
    cev = ce[myrow];
    cxv = out[myrow];
  }

  for (int t = 1; t <= S_LEN; ++t) {
    // ---- poll: all 2048 tags of s_{t-1} in buf[(t-1)&1] ----
    u64* src = ((t - 1) & 1) ? b1 : b0;
    const u32 want = (u32)(t - 1);
    u64 v0 = __hip_atomic_load(&src[base + 0], __ATOMIC_RELAXED,
                               __HIP_MEMORY_SCOPE_AGENT);
    u64 v1 = __hip_atomic_load(&src[base + 1], __ATOMIC_RELAXED,
                               __HIP_MEMORY_SCOPE_AGENT);
    while (!(((u32)v0 == want) & ((u32)v1 == want))) {
      if ((u32)v0 != want)
        v0 = __hip_atomic_load(&src[base + 0], __ATOMIC_RELAXED,
                               __HIP_MEMORY_SCOPE_AGENT);
      if ((u32)v1 != want)
        v1 = __hip_atomic_load(&src[base + 1], __ATOMIC_RELAXED,
                               __HIP_MEMORY_SCOPE_AGENT);
    }

    // ---- issue NEXT step's stream loads now; with the bare barrier below
    // they stay in flight and resolve during the next poll phase ----
    float ncev = 0.f, ncxv = 0.f;
    if (owner && t < S_LEN) {
      ncev = ce[(size_t)t * DIM + myrow];
      ncxv = out[(size_t)t * DIM + myrow];
    }

    // ---- broadcast via double-buffered LDS; values ride in the poll data ----
    float* stw = st[t & 1];
    {
      float2 sv2;
      sv2.x = __uint_as_float((u32)(v0 >> 32));
      sv2.y = __uint_as_float((u32)(v1 >> 32));
      *(float2*)&stw[slot2] = sv2;
    }
    // bare barrier: drain LDS only — vmem (prefetches, stores) stays in flight
    asm volatile("s_waitcnt lgkmcnt(0)\n\ts_barrier" ::: "memory");

    // ---- y partial: 2 rows x 32 cols per lane, packed dual-FP32 FMA ----
    f32x2 a0 = {}, a1 = {};
    #pragma unroll
    for (int jj = 0; jj < 8; ++jj) {
      const float4 sv = *(const float4*)&stw[32 * l + 4 * (jj ^ (l & 7))];
      const f32x2 s01 = (f32x2){sv.x, sv.y};
      const f32x2 s23 = (f32x2){sv.z, sv.w};
      a0 += w2[0][2 * jj + 0] * s01;   // v_pk_fma_f32
      a0 += w2[0][2 * jj + 1] * s23;
      a1 += w2[1][2 * jj + 0] * s01;
      a1 += w2[1][2 * jj + 1] * s23;
    }
    float p0 = a0.x + a0.y;   // partial for row 2w   over cols [32l,32l+32)
    float p1 = a1.x + a1.y;   // partial for row 2w+1

    // ---- reduce: xor32 scatter + xor16 butterfly + 4x DPP butterfly ----
    // L1 (xor32): lanes <32 keep row 2w, lanes >=32 keep row 2w+1
    float send = (l & 32) ? p0 : p1;
    float got  = __shfl_xor(send, 32, 64);
    float b    = ((l & 32) ? p1 : p0) + got;
    // L2 (xor16): butterfly within each 32-lane half
    b += __shfl_xor(b, 16, 64);
    // L3-L6: 16-lane row butterfly via DPP (all lanes end with row total)
    b = dpp_add<0xB1>(b);    // quad_perm [1,0,3,2]  : xor1
    b = dpp_add<0x4E>(b);    // quad_perm [2,3,0,1]  : xor2
    b = dpp_add<0x141>(b);   // row_half_mirror      : i^7 within 8
    b = dpp_add<0x140>(b);   // row_mirror           : i^15 within 16

    if (owner) {
      float y = b + cxv;
      hcm = fmaxf(hcm, cev);
      float e = __expf(-y);
      float s = hcm * __builtin_amdgcn_rcpf(1.0f + e);
      // tag store FIRST — it is the critical path for every other WG
      u64* dst = (t & 1) ? b1 : b0;
      u64 pk = ((u64)__float_as_uint(s) << 32) | (u64)(u32)t;
      __hip_atomic_store(&dst[myrow], pk, __ATOMIC_RELAXED,
                         __HIP_MEMORY_SCOPE_AGENT);
      asm volatile("" ::: "memory");  // keep result store behind the tag store
      out[(size_t)(t - 1) * DIM + myrow] = s;
      s_last = s;
    }
    cev = ncev;
    cxv = ncxv;
  }

  if (owner) out[(size_t)S_LEN * DIM + myrow] = s_last;
}

// ---------------------------------------------------------------------------
extern "C" void kernel_launch(void* const* d_in, const int* in_sizes, int n_in,
                              void* d_out, int out_size, void* d_ws, size_t ws_size,
                              hipStream_t stream) {
  const float* ce = (const float*)d_in[0];
  const float* W  = (const float*)d_in[1];
  const float* b  = (const float*)d_in[2];
  float* out = (float*)d_out;
  u64* pairs = (u64*)d_ws;   // 2 * 2048 * 8B = 32 KB

  hipLaunchKernelGGL(init_pairs, dim3(16), dim3(256), 0, stream, pairs);
  hipLaunchKernelGGL(gemm_ctx, dim3(DIM / 64, S_LEN / 64), dim3(256), 0, stream,
                     ce, W, b, out);
  hipLaunchKernelGGL(recur, dim3(64), dim3(1024), 0, stream, W, ce, out, pairs);
}

// Round 7
// 15029.893 us; speedup vs baseline: 1.0923x; 1.0923x over previous
//
#include <hip/hip_runtime.h>
#include <stdint.h>

#define S_LEN 8192
#define DIM   2048
#define W2    4096   // W row length = 2*DIM

typedef __attribute__((ext_vector_type(8))) __bf16 bf16x8;
typedef __attribute__((ext_vector_type(4))) float  floatx4;
typedef __attribute__((ext_vector_type(2))) float  f32x2;
typedef unsigned long long u64;
typedef unsigned int       u32;

// ---------------------------------------------------------------------------
// Init: tag buffers. buf0 = s_0 = -1.0 with tag 0; buf1 tag 0 (never matches
// its first expected tag 1, so readers spin until written).
// ---------------------------------------------------------------------------
__global__ void init_pairs(u64* __restrict__ pairs) {
  int i = blockIdx.x * 256 + threadIdx.x;
  if (i < 2 * DIM) {
    pairs[i] = ((u64)__float_as_uint(-1.0f) << 32) | 0ull;
  }
}

// ---------------------------------------------------------------------------
// GEMM: C[m][n] = sum_k A[m][k] * W[n*4096 + 2048 + k] + b[n]
// (unchanged — correct, and small vs the recurrence)
// ---------------------------------------------------------------------------
__device__ inline bf16x8 pack_bf8(float4 a, float4 b) {
  bf16x8 h;
  h[0] = (__bf16)a.x; h[1] = (__bf16)a.y; h[2] = (__bf16)a.z; h[3] = (__bf16)a.w;
  h[4] = (__bf16)b.x; h[5] = (__bf16)b.y; h[6] = (__bf16)b.z; h[7] = (__bf16)b.w;
  return h;
}

__global__ __launch_bounds__(256) void gemm_ctx(const float* __restrict__ A,
                                                const float* __restrict__ W,
                                                const float* __restrict__ bias,
                                                float* __restrict__ C) {
  __shared__ __bf16 As[64][72];
  __shared__ __bf16 Bs[64][72];
  const int tid  = threadIdx.x;
  const int m0   = blockIdx.y * 64;
  const int n0   = blockIdx.x * 64;
  const int w    = tid >> 6;
  const int lane = tid & 63;
  const int wm   = w >> 1, wn = w & 1;
  const int r    = tid >> 2;
  const int seg  = tid & 3;

  floatx4 acc[2][2] = {};

  for (int k0 = 0; k0 < DIM; k0 += 64) {
    {
      const float* pa = A + (size_t)(m0 + r) * DIM + k0 + seg * 16;
      const float* pb = W + (size_t)(n0 + r) * W2 + DIM + k0 + seg * 16;
      float4 a0 = ((const float4*)pa)[0], a1 = ((const float4*)pa)[1];
      float4 a2 = ((const float4*)pa)[2], a3 = ((const float4*)pa)[3];
      float4 b0 = ((const float4*)pb)[0], b1 = ((const float4*)pb)[1];
      float4 b2 = ((const float4*)pb)[2], b3 = ((const float4*)pb)[3];
      *(bf16x8*)&As[r][seg * 16]     = pack_bf8(a0, a1);
      *(bf16x8*)&As[r][seg * 16 + 8] = pack_bf8(a2, a3);
      *(bf16x8*)&Bs[r][seg * 16]     = pack_bf8(b0, b1);
      *(bf16x8*)&Bs[r][seg * 16 + 8] = pack_bf8(b2, b3);
    }
    __syncthreads();
    #pragma unroll
    for (int kk = 0; kk < 64; kk += 32) {
      const int ks = kk + (lane >> 4) * 8;
      bf16x8 af[2], bfr[2];
      af[0]  = *(const bf16x8*)&As[32 * wm +      (lane & 15)][ks];
      af[1]  = *(const bf16x8*)&As[32 * wm + 16 + (lane & 15)][ks];
      bfr[0] = *(const bf16x8*)&Bs[32 * wn +      (lane & 15)][ks];
      bfr[1] = *(const bf16x8*)&Bs[32 * wn + 16 + (lane & 15)][ks];
      #pragma unroll
      for (int im = 0; im < 2; ++im)
        #pragma unroll
        for (int in = 0; in < 2; ++in)
          acc[im][in] = __builtin_amdgcn_mfma_f32_16x16x32_bf16(
              af[im], bfr[in], acc[im][in], 0, 0, 0);
    }
    __syncthreads();
  }

  #pragma unroll
  for (int in = 0; in < 2; ++in) {
    const int col = n0 + 32 * wn + 16 * in + (lane & 15);
    const float bv = bias[col];
    #pragma unroll
    for (int im = 0; im < 2; ++im) {
      const int rbase = m0 + 32 * wm + 16 * im + (lane >> 4) * 4;
      #pragma unroll
      for (int q = 0; q < 4; ++q)
        C[(size_t)(rbase + q) * DIM + col] = acc[im][in][q] + bv;
    }
  }
}

// DPP butterfly add: x += x_from_lane(partner), partner an involution within
// the 16-lane row -> direction-proof. HW-verified in v8 (passed correctness).
// 0xB1 = quad_perm:[1,0,3,2] (xor1)   0x4E = quad_perm:[2,3,0,1] (xor2)
// 0x141 = row_half_mirror (i^7 in 8)  0x140 = row_mirror (i^15 in 16)
// After xor1+xor2 the quad is uniform, so 0x141 == xor4-combine and
// 0x140 == xor8-combine.
template <int CTRL>
__device__ __forceinline__ float dpp_add(float x) {
  int s = __builtin_amdgcn_update_dpp(0, __float_as_int(x), CTRL, 0xF, 0xF, true);
  return x + __int_as_float(s);
}

// ---------------------------------------------------------------------------
// Persistent recurrence v9: 64 WGs x 512 threads (8 waves) — v6's proven
// structure (15.55ms). WG k owns rows [32k,32k+32); wave w owns 4 rows;
// lane l owns cols [32l,32l+32).
// vs v6: reduce re-ordered — scatter at TOP levels (xor32 x2 + xor16, 3
// shuffles) then 4 quad-uniform DPP adds (v8-verified ctrls) for the 16-lane
// combine. 7 dependent ds_bpermute (~210cy) -> 3 shfl + 4 VALU DPP (~100cy).
// Owners at lanes 0/16/32/48; row = ((l>>5)&1)<<1 | ((l>>4)&1).
// vs v8 (16.39ms REGRESSION): 1024-thread WGs reverted — owner state got
// scratch-spilled per step (WRITE +131MB = 8B/owner/step), bank conflicts 2x.
// POLL IS v4's EXACT FORM (sacred): both attempts to change its instruction
// form regressed via FETCH_SIZE blowup (v3 +134MB, v5 +260MB).
// ---------------------------------------------------------------------------
__global__ __launch_bounds__(512, 1) void recur(const float* __restrict__ W,
                                                const float* __restrict__ ce,
                                                float* __restrict__ out,
                                                u64* __restrict__ pairs) {
  __shared__ __align__(16) float st[2][DIM];
  const int tid = threadIdx.x;
  const int w = tid >> 6, l = tid & 63;
  const int i0 = blockIdx.x * 32;

  // W_state slab into registers: 4 rows x 16 f32x2 (32 cols) per lane
  f32x2 w2[4][16];
  #pragma unroll
  for (int r2 = 0; r2 < 4; ++r2) {
    const float* wp = W + (size_t)(i0 + 4 * w + r2) * W2 + 32 * l;
    #pragma unroll
    for (int j = 0; j < 8; ++j) {
      float4 v = ((const float4*)wp)[j];
      w2[r2][2 * j + 0] = (f32x2){v.x, v.y};
      w2[r2][2 * j + 1] = (f32x2){v.z, v.w};
    }
  }

  // Row held after the top-level scatter: l=0 -> 0, 16 -> 1, 32 -> 2, 48 -> 3
  const int rmap  = (((l >> 5) & 1) << 1) | ((l >> 4) & 1);
  const int myrow = i0 + 4 * w + rmap;      // valid when owner
  const bool owner = ((l & 15) == 0);       // lanes 0,16,32,48 of each wave
  float hcm = -3.0e38f;                     // running cummax
  float s_last = 0.f;
  u64* b0 = pairs;
  u64* b1 = pairs + DIM;
  const int base = tid * 4;                 // 512 threads x 4 entries = 2048
  // LDS store slot base (XOR swizzle, consistent with the rotated read)
  const int slot4 = (4 * tid) ^ (((tid >> 3) & 7) << 2);

  // step-1 operands (prefetched before the loop)
  float cev = 0.f, cxv = 0.f;
  if (owner) {
    cev = ce[myrow];
    cxv = out[myrow];
  }

  for (int t = 1; t <= S_LEN; ++t) {
    // ---- poll: all 2048 tags of s_{t-1} in buf[(t-1)&1] ----
    u64* src = ((t - 1) & 1) ? b1 : b0;
    const u32 want = (u32)(t - 1);
    u64 v[4];
    #pragma unroll
    for (int q = 0; q < 4; ++q)
      v[q] = __hip_atomic_load(&src[base + q], __ATOMIC_RELAXED,
                               __HIP_MEMORY_SCOPE_AGENT);
    for (;;) {
      u32 bad = 0;
      #pragma unroll
      for (int q = 0; q < 4; ++q)
        bad |= ((u32)v[q] != want) ? (1u << q) : 0u;
      if (!bad) break;
      #pragma unroll
      for (int q = 0; q < 4; ++q)
        if ((bad >> q) & 1u)
          v[q] = __hip_atomic_load(&src[base + q], __ATOMIC_RELAXED,
                                   __HIP_MEMORY_SCOPE_AGENT);
    }

    // ---- issue NEXT step's stream loads now; with the bare barrier below
    // they stay in flight and resolve during the next poll phase ----
    float ncev = 0.f, ncxv = 0.f;
    if (owner && t < S_LEN) {
      ncev = ce[(size_t)t * DIM + myrow];
      ncxv = out[(size_t)t * DIM + myrow];
    }

    // ---- broadcast via double-buffered LDS; values ride in the poll data ----
    float* stw = st[t & 1];
    {
      float4 sv4;
      sv4.x = __uint_as_float((u32)(v[0] >> 32));
      sv4.y = __uint_as_float((u32)(v[1] >> 32));
      sv4.z = __uint_as_float((u32)(v[2] >> 32));
      sv4.w = __uint_as_float((u32)(v[3] >> 32));
      *(float4*)&stw[slot4] = sv4;
    }
    // bare barrier: drain LDS only — vmem (prefetches, stores) stays in flight
    asm volatile("s_waitcnt lgkmcnt(0)\n\ts_barrier" ::: "memory");

    // ---- y partial: 4 rows x 32 cols per lane, packed dual-FP32 FMA ----
    f32x2 acc2[4] = {};
    #pragma unroll
    for (int jj = 0; jj < 8; ++jj) {
      const float4 sv = *(const float4*)&stw[32 * l + 4 * (jj ^ (l & 7))];
      const f32x2 s01 = (f32x2){sv.x, sv.y};
      const f32x2 s23 = (f32x2){sv.z, sv.w};
      #pragma unroll
      for (int r2 = 0; r2 < 4; ++r2) {
        acc2[r2] += w2[r2][2 * jj + 0] * s01;   // v_pk_fma_f32
        acc2[r2] += w2[r2][2 * jj + 1] * s23;   // v_pk_fma_f32
      }
    }
    float p0 = acc2[0].x + acc2[0].y;
    float p1 = acc2[1].x + acc2[1].y;
    float p2 = acc2[2].x + acc2[2].y;
    float p3 = acc2[3].x + acc2[3].y;

    // ---- reduce: top-level scatter (3 shfl) + 4 DPP butterfly adds ----
    // L1 (xor32): lanes <32 keep rows {0,1}, lanes >=32 keep rows {2,3}
    float sA = (l & 32) ? p0 : p2;
    float sB = (l & 32) ? p1 : p3;
    float gA = __shfl_xor(sA, 32, 64);
    float gB = __shfl_xor(sB, 32, 64);
    float q0 = ((l & 32) ? p2 : p0) + gA;   // row (l&32 ? 2 : 0)
    float q1 = ((l & 32) ? p3 : p1) + gB;   // row (l&32 ? 3 : 1)
    // L2 (xor16): keep one row; row held = rmap
    float s2 = (l & 16) ? q0 : q1;
    float g2 = __shfl_xor(s2, 16, 64);
    float d  = ((l & 16) ? q1 : q0) + g2;
    // L3-L6: 16-lane combine via DPP butterfly (v8-verified)
    d = dpp_add<0xB1>(d);    // xor1
    d = dpp_add<0x4E>(d);    // xor2
    d = dpp_add<0x141>(d);   // quad-uniform -> xor4-combine
    d = dpp_add<0x140>(d);   // 8-uniform   -> xor8-combine

    if (owner) {
      float y = d + cxv;
      hcm = fmaxf(hcm, cev);
      float e = __expf(-y);
      float s = hcm * __builtin_amdgcn_rcpf(1.0f + e);
      // tag store FIRST — it is the critical path for every other WG
      u64* dst = (t & 1) ? b1 : b0;
      u64 pk = ((u64)__float_as_uint(s) << 32) | (u64)(u32)t;
      __hip_atomic_store(&dst[myrow], pk, __ATOMIC_RELAXED,
                         __HIP_MEMORY_SCOPE_AGENT);
      asm volatile("" ::: "memory");  // keep result store behind the tag store
      out[(size_t)(t - 1) * DIM + myrow] = s;
      s_last = s;
    }
    cev = ncev;
    cxv = ncxv;
  }

  if (owner) out[(size_t)S_LEN * DIM + myrow] = s_last;
}

// ---------------------------------------------------------------------------
extern "C" void kernel_launch(void* const* d_in, const int* in_sizes, int n_in,
                              void* d_out, int out_size, void* d_ws, size_t ws_size,
                              hipStream_t stream) {
  const float* ce = (const float*)d_in[0];
  const float* W  = (const float*)d_in[1];
  const float* b  = (const float*)d_in[2];
  float* out = (float*)d_out;
  u64* pairs = (u64*)d_ws;   // 2 * 2048 * 8B = 32 KB

  hipLaunchKernelGGL(init_pairs, dim3(16), dim3(256), 0, stream, pairs);
  hipLaunchKernelGGL(gemm_ctx, dim3(DIM / 64, S_LEN / 64), dim3(256), 0, stream,
                     ce, W, b, out);
  hipLaunchKernelGGL(recur, dim3(64), dim3(512), 0, stream, W, ce, out, pairs);
}